// Round 4
// baseline (1767.354 us; speedup 1.0000x reference)
//
#include <hip/hip_runtime.h>
#include <stdint.h>

// genericPINN v5: SPB=32 (halves L2 weight traffic -> L2/LDS/MFMA pipes balanced),
// v4's tiled zero-VALU LDS layout [ks][kh][m^swz][e], rolled pair K-loop (no spills),
// reg dbuf A and B. 8 waves x (128 rows x 64 cols), 1 block/CU, 256-reg budget.

#define B_SZ   65536
#define NN     512
#define NL     8
#define SPB    32            // samples per block
#define MROWS  128           // 4 * SPB stream-rows
#define MT     4             // 128/32 M-tiles per wave
#define NKS    32            // K-steps of 16 per layer
#define NG2    (NL*NKS)      // 256 weight groups of 16 KiB
#define LDS_A  (MROWS*1024)  // 131072 = 32 k-tiles x 4096 B
#define LDS_TOTAL (LDS_A + 2048)

typedef _Float16 f16x8  __attribute__((ext_vector_type(8)));
typedef float    f32x16 __attribute__((ext_vector_type(16)));

__device__ __forceinline__ uint16_t f2h_bits(float f) {
  union { _Float16 h; uint16_t u; } v; v.h = (_Float16)f; return v.u;
}
__device__ __forceinline__ float h2f(uint16_t b) {
  union { uint16_t u; _Float16 h; } v; v.u = b; return (float)v.h;
}

// A element (m,k) byte offset: tile=k>>4 (stride 4096), khp=(k>>3)&1 (stride 2048),
// m' = m ^ (khp<<2) ^ ((tile&1)<<1), e=k&7
__device__ __forceinline__ int abyte(int m, int k) {
  const int tile = k >> 4, khp = (k >> 3) & 1, e = k & 7;
  const int mp = m ^ (khp << 2) ^ ((tile & 1) << 1);
  return (tile << 12) + (khp << 11) + (mp << 4) + (e << 1);
}

// ---- prep: Ws (L,512,512) fp32 -> f16 image for per-wave 32x32x16 B-frag reg loads.
// img[g2][wv][Nt][lane][16B], g2 = l*32 + ks  (16 KiB per group).
// frag for lane: W[ks*16 + (lane>>5)*8 + e][wv*64 + Nt*32 + (lane&31)], e=0..7
__global__ __launch_bounds__(512) void prep_weights(const float* __restrict__ Ws,
                                                    uint16_t* __restrict__ img) {
  const int g2 = blockIdx.x;              // 0..255
  const int l  = g2 >> 5, ks = g2 & 31;
  const float* src = Ws + ((size_t)l << 18);
  char* dst = (char*)img + ((size_t)g2 << 14);
  #pragma unroll
  for (int it = 0; it < 2; ++it) {
    const int fidx = threadIdx.x + it*512;          // 0..1023 fragments
    const int ln  = fidx & 63, sub = fidx >> 6;     // sub = wv*2 + Nt
    const int n     = (sub >> 1)*64 + (sub & 1)*32 + (ln & 31);
    const int kbase = ks*16 + (ln >> 5)*8;
    uint16_t h[8];
    #pragma unroll
    for (int e = 0; e < 8; ++e)
      h[e] = f2h_bits(src[(size_t)(kbase + e)*512 + n]);
    uint4 pk;
    pk.x = (uint32_t)h[0] | ((uint32_t)h[1] << 16);
    pk.y = (uint32_t)h[2] | ((uint32_t)h[3] << 16);
    pk.z = (uint32_t)h[4] | ((uint32_t)h[5] << 16);
    pk.w = (uint32_t)h[6] | ((uint32_t)h[7] << 16);
    *(uint4*)(dst + (size_t)fidx*16) = pk;
  }
}

__global__ __launch_bounds__(512, 2) void pinn_fused(
    const float* __restrict__ inputs, const float* __restrict__ Brff,
    const float* __restrict__ bs, const float* __restrict__ alphas,
    const float* __restrict__ Wf, const float* __restrict__ scl,
    const uint16_t* __restrict__ wimg, float* __restrict__ out)
{
  extern __shared__ char smem[];

  const int tid  = threadIdx.x;
  const int lane = tid & 63;
  const int wv   = tid >> 6;        // wave 0..7
  const int l31  = lane & 31;
  const int kh   = lane >> 5;       // k-half (0/1)
  const int sbase = blockIdx.x * SPB;   // 2048 * 32 == 65536

  const char* wp  = (const char*)wimg;
  const int  boff = wv*2048 + lane*16;  // per-lane B image offset

  f16x8 bA0, bA1, bB0, bB1;
  // initial B prefetch for g2 = 0,1 (hides under layer-0 compute)
  bA0 = *(const f16x8*)(wp + boff);
  bA1 = *(const f16x8*)(wp + boff + 1024);
  bB0 = *(const f16x8*)(wp + 16384 + boff);
  bB1 = *(const f16x8*)(wp + 16384 + boff + 1024);

  // ---- layer 0: u0 = [sin z, cos z]; du0_c = [cos z * B_c, -sin z * B_c] ----
  {
    const int k = tid, col = k & 255;
    const bool iscos = (k >= 256);
    const float b0 = Brff[col];
    const float b1 = Brff[256 + col];
    const float b2 = Brff[512 + col];
    const float b3 = Brff[768 + col];
    const int cb  = ((k >> 4) << 12) + (((k >> 3) & 1) << 11) + ((k & 7) << 1);
    const int xm  = (((k >> 3) & 1) << 2) ^ (((k >> 4) & 1) << 1);
    for (int s = 0; s < SPB; ++s) {
      const float4 x = *(const float4*)(inputs + ((size_t)(sbase + s) << 2));
      const float z = x.x*b0 + x.y*b1 + x.z*b2 + x.w*b3;
      const float szn = __sinf(z), czn = __cosf(z);
      const float u0 = iscos ? czn : szn;
      const float dz = iscos ? -szn : czn;
      const int m0 = 4*s;
      *(uint16_t*)(smem + cb + (((m0+0) ^ xm) << 4)) = f2h_bits(u0);
      *(uint16_t*)(smem + cb + (((m0+1) ^ xm) << 4)) = f2h_bits(dz*b1);
      *(uint16_t*)(smem + cb + (((m0+2) ^ xm) << 4)) = f2h_bits(dz*b2);
      *(uint16_t*)(smem + cb + (((m0+3) ^ xm) << 4)) = f2h_bits(dz*b3);
    }
  }
  __syncthreads();

  // A-frag per-lane vaddrs: even/odd k-tile parity
  const char* paE = smem + ((kh << 11) + ((l31 ^ (kh << 2)) << 4));
  const char* paO = smem + ((kh << 11) + ((l31 ^ (kh << 2) ^ 2) << 4));

  f16x8 aC[MT], aN[MT];
  #pragma unroll
  for (int Mt = 0; Mt < MT; ++Mt)
    aC[Mt] = *(const f16x8*)(paE + Mt*512);          // ks = 0

  const f32x16 zz = {0,0,0,0,0,0,0,0,0,0,0,0,0,0,0,0};
  f32x16 acc[MT][2];

  for (int l = 0; l < NL; ++l) {
    #pragma unroll
    for (int Mt = 0; Mt < MT; ++Mt) { acc[Mt][0] = zz; acc[Mt][1] = zz; }
    const int g2b = l*NKS;
    int aoff = 0;

    #pragma unroll 1
    for (int t = 0; t < NKS/2; ++t) {
      // prefetch A k-tile (ks+1)
      #pragma unroll
      for (int Mt = 0; Mt < MT; ++Mt)
        aN[Mt] = *(const f16x8*)(paO + aoff + 4096 + Mt*512);
      __builtin_amdgcn_s_setprio(1);
      #pragma unroll
      for (int Mt = 0; Mt < MT; ++Mt) {
        acc[Mt][0] = __builtin_amdgcn_mfma_f32_32x32x16_f16(aC[Mt], bA0, acc[Mt][0], 0, 0, 0);
        acc[Mt][1] = __builtin_amdgcn_mfma_f32_32x32x16_f16(aC[Mt], bA1, acc[Mt][1], 0, 0, 0);
      }
      __builtin_amdgcn_s_setprio(0);
      {
        const int gt = g2b + 2*t + 2;            // reload freed B buffer, 2 ks ahead
        if (gt < NG2) {
          const char* p = wp + ((size_t)gt << 14) + boff;
          bA0 = *(const f16x8*)p;
          bA1 = *(const f16x8*)(p + 1024);
        }
      }
      if (t + 1 < NKS/2) {                       // prefetch A k-tile (ks+2)
        #pragma unroll
        for (int Mt = 0; Mt < MT; ++Mt)
          aC[Mt] = *(const f16x8*)(paE + aoff + 8192 + Mt*512);
      }
      __builtin_amdgcn_s_setprio(1);
      #pragma unroll
      for (int Mt = 0; Mt < MT; ++Mt) {
        acc[Mt][0] = __builtin_amdgcn_mfma_f32_32x32x16_f16(aN[Mt], bB0, acc[Mt][0], 0, 0, 0);
        acc[Mt][1] = __builtin_amdgcn_mfma_f32_32x32x16_f16(aN[Mt], bB1, acc[Mt][1], 0, 0, 0);
      }
      __builtin_amdgcn_s_setprio(0);
      {
        const int gt = g2b + 2*t + 3;
        if (gt < NG2) {
          const char* p = wp + ((size_t)gt << 14) + boff;
          bB0 = *(const f16x8*)p;
          bB1 = *(const f16x8*)(p + 1024);
        }
      }
      aoff += 8192;
    }
    __syncthreads();   // all A-reads of layer l complete before overwrite

    // ---- epilogue: h=(1+a)(dot+b); u'=sin h; du'=(1+a)cos(h)*dot_t ----
    // 32x32 C/D layout: col = lane&31, row = (r&3) + 8*(r>>2) + 4*(lane>>5)
    const float opa = 1.0f + alphas[l];
    #pragma unroll
    for (int Nt = 0; Nt < 2; ++Nt) {
      const int nc = wv*64 + Nt*32 + l31;
      const int cb = ((nc >> 4) << 12) + (((nc >> 3) & 1) << 11) + ((nc & 7) << 1);
      const int xm = (((nc >> 3) & 1) << 2) ^ (((nc >> 4) & 1) << 1);
      const float bias = bs[l*NN + nc];
      #pragma unroll
      for (int Mt = 0; Mt < MT; ++Mt) {
        const f32x16 c = acc[Mt][Nt];
        #pragma unroll
        for (int j = 0; j < 4; ++j) {
          const float hh = opa * (c[4*j] + bias);
          const float un = __sinf(hh);
          const float fc = opa * __cosf(hh);
          const float vv[4] = { un, fc*c[4*j+1], fc*c[4*j+2], fc*c[4*j+3] };
          const int m0 = Mt*32 + 8*j + 4*kh;
          #pragma unroll
          for (int s = 0; s < 4; ++s) {
            const int m = m0 + s;
            *(uint16_t*)(smem + cb + ((m ^ xm) << 4)) = f2h_bits(vv[s]);
          }
        }
      }
    }
    __syncthreads();

    if (l + 1 < NL) {   // preload ks=0 of next layer
      #pragma unroll
      for (int Mt = 0; Mt < MT; ++Mt)
        aC[Mt] = *(const f16x8*)(paE + Mt*512);
    }
  }

  // ---- final projection: dp[m][o] = sum_k A[m][k]*Wf[k][o] * scale[o] ----
  float* dp = (float*)(smem + LDS_A);
  const float4 sc4 = *(const float4*)scl;
  for (int rr = 0; rr < MROWS/8; ++rr) {     // 16 rows per wave
    const int m = wv*(MROWS/8) + rr;
    float p0 = 0.f, p1 = 0.f, p2 = 0.f, p3 = 0.f;
    #pragma unroll
    for (int j = 0; j < 8; ++j) {
      const int k = lane + j*64;
      float a = h2f(*(const uint16_t*)(smem + abyte(m, k)));
      float4 wf = ((const float4*)Wf)[k];
      p0 += a*wf.x; p1 += a*wf.y; p2 += a*wf.z; p3 += a*wf.w;
    }
    #pragma unroll
    for (int d = 1; d < 64; d <<= 1) {
      p0 += __shfl_xor(p0, d, 64);
      p1 += __shfl_xor(p1, d, 64);
      p2 += __shfl_xor(p2, d, 64);
      p3 += __shfl_xor(p3, d, 64);
    }
    if (lane == 0) {
      float4* o = (float4*)(dp + m*4);
      *o = make_float4(p0*sc4.x, p1*sc4.y, p2*sc4.z, p3*sc4.w);
    }
  }
  __syncthreads();

  // rows 4s+1=dPdz, 4s+2=dPdx, 4s+3=dPdy
  // u = dPdy[2]-dPdz[1]+dPdx[3]; v = dPdz[0]-dPdx[2]+dPdy[3]; w = dPdx[1]-dPdy[0]+dPdz[3]
  if (tid < SPB*3) {
    const int sl = tid / 3, c = tid - sl*3;
    const float* d1 = dp + (sl*4 + 1)*4;
    const float* d2 = dp + (sl*4 + 2)*4;
    const float* d3 = dp + (sl*4 + 3)*4;
    float val;
    if (c == 0)      val = d3[2] - d1[1] + d2[3];
    else if (c == 1) val = d1[0] - d2[2] + d3[3];
    else             val = d2[1] - d3[0] + d1[3];
    out[(size_t)(sbase + sl)*3 + c] = val;
  }
}

extern "C" void kernel_launch(void* const* d_in, const int* in_sizes, int n_in,
                              void* d_out, int out_size, void* d_ws, size_t ws_size,
                              hipStream_t stream) {
  const float* inputs = (const float*)d_in[0];
  const float* Brff   = (const float*)d_in[1];
  const float* Ws     = (const float*)d_in[2];
  const float* bsp    = (const float*)d_in[3];
  const float* alph   = (const float*)d_in[4];
  const float* Wfp    = (const float*)d_in[5];
  const float* sclp   = (const float*)d_in[6];
  uint16_t* wimg = (uint16_t*)d_ws;           // needs 4 MiB workspace

  prep_weights<<<NG2, 512, 0, stream>>>(Ws, wimg);
  const int nblocks = B_SZ / SPB;             // 2048
  pinn_fused<<<nblocks, 512, LDS_TOTAL, stream>>>(inputs, Brff, bsp, alph, Wfp, sclp,
                                                  wimg, (float*)d_out);
}

// Round 5
// 1465.823 us; speedup vs baseline: 1.2057x; 1.2057x over previous
//
#include <hip/hip_runtime.h>
#include <stdint.h>

// genericPINN v6: v3 geometry (SPB=16, 2 blocks/CU, 16 waves/CU) + v4 tiled
// conflict-free LDS layout [ks][kh][m^swz][e] + v5 rolled non-spilling pair loop.
// 8 waves x (64 rows x 64 cols), 32x32x16 f16 MFMA, reg dbuf A and B.

#define B_SZ   65536
#define NN     512
#define NL     8
#define SPB    16            // samples per block
#define MROWS  64            // 4 * SPB stream-rows
#define MT     2             // 64/32 M-tiles per wave
#define NKS    32            // K-steps of 16 per layer
#define NG2    (NL*NKS)      // 256 weight groups of 16 KiB
#define LDS_A  (MROWS*1024)  // 65536 = 32 k-tiles x 2048 B
#define LDS_TOTAL (LDS_A + 1024)

typedef _Float16 f16x8  __attribute__((ext_vector_type(8)));
typedef float    f32x16 __attribute__((ext_vector_type(16)));

__device__ __forceinline__ uint16_t f2h_bits(float f) {
  union { _Float16 h; uint16_t u; } v; v.h = (_Float16)f; return v.u;
}
__device__ __forceinline__ float h2f(uint16_t b) {
  union { uint16_t u; _Float16 h; } v; v.u = b; return (float)v.h;
}

// A element (m,k) byte offset: tile=k>>4 (stride 2048), khp=(k>>3)&1 (stride 1024),
// m' = m ^ (khp<<2) ^ ((tile&1)<<1), e=k&7
__device__ __forceinline__ int abyte(int m, int k) {
  const int tile = k >> 4, khp = (k >> 3) & 1, e = k & 7;
  const int mp = m ^ (khp << 2) ^ ((tile & 1) << 1);
  return (tile << 11) + (khp << 10) + (mp << 4) + (e << 1);
}

// ---- prep: Ws (L,512,512) fp32 -> f16 image for per-wave 32x32x16 B-frag reg loads.
// img[g2][wv][Nt][lane][16B], g2 = l*32 + ks  (16 KiB per group).
// frag for lane: W[ks*16 + (lane>>5)*8 + e][wv*64 + Nt*32 + (lane&31)], e=0..7
__global__ __launch_bounds__(512) void prep_weights(const float* __restrict__ Ws,
                                                    uint16_t* __restrict__ img) {
  const int g2 = blockIdx.x;              // 0..255
  const int l  = g2 >> 5, ks = g2 & 31;
  const float* src = Ws + ((size_t)l << 18);
  char* dst = (char*)img + ((size_t)g2 << 14);
  #pragma unroll
  for (int it = 0; it < 2; ++it) {
    const int fidx = threadIdx.x + it*512;          // 0..1023 fragments
    const int ln  = fidx & 63, sub = fidx >> 6;     // sub = wv*2 + Nt
    const int n     = (sub >> 1)*64 + (sub & 1)*32 + (ln & 31);
    const int kbase = ks*16 + (ln >> 5)*8;
    uint16_t h[8];
    #pragma unroll
    for (int e = 0; e < 8; ++e)
      h[e] = f2h_bits(src[(size_t)(kbase + e)*512 + n]);
    uint4 pk;
    pk.x = (uint32_t)h[0] | ((uint32_t)h[1] << 16);
    pk.y = (uint32_t)h[2] | ((uint32_t)h[3] << 16);
    pk.z = (uint32_t)h[4] | ((uint32_t)h[5] << 16);
    pk.w = (uint32_t)h[6] | ((uint32_t)h[7] << 16);
    *(uint4*)(dst + (size_t)fidx*16) = pk;
  }
}

__global__ __launch_bounds__(512, 4) void pinn_fused(
    const float* __restrict__ inputs, const float* __restrict__ Brff,
    const float* __restrict__ bs, const float* __restrict__ alphas,
    const float* __restrict__ Wf, const float* __restrict__ scl,
    const uint16_t* __restrict__ wimg, float* __restrict__ out)
{
  extern __shared__ char smem[];

  const int tid  = threadIdx.x;
  const int lane = tid & 63;
  const int wv   = tid >> 6;        // wave 0..7
  const int l31  = lane & 31;
  const int kh   = lane >> 5;       // k-half (0/1)
  const int sbase = blockIdx.x * SPB;   // 4096 * 16 == 65536

  const char* wp  = (const char*)wimg;
  const int  boff = wv*2048 + lane*16;  // per-lane B image offset

  f16x8 bA0, bA1, bB0, bB1;
  // initial B prefetch for g2 = 0,1 (hides under layer-0 compute)
  bA0 = *(const f16x8*)(wp + boff);
  bA1 = *(const f16x8*)(wp + boff + 1024);
  bB0 = *(const f16x8*)(wp + 16384 + boff);
  bB1 = *(const f16x8*)(wp + 16384 + boff + 1024);

  // ---- layer 0: u0 = [sin z, cos z]; du0_c = [cos z * B_c, -sin z * B_c] ----
  {
    const int k = tid, col = k & 255;
    const bool iscos = (k >= 256);
    const float b0 = Brff[col];
    const float b1 = Brff[256 + col];
    const float b2 = Brff[512 + col];
    const float b3 = Brff[768 + col];
    const int cb  = ((k >> 4) << 11) + (((k >> 3) & 1) << 10) + ((k & 7) << 1);
    const int xm  = (((k >> 3) & 1) << 2) ^ (((k >> 4) & 1) << 1);
    for (int s = 0; s < SPB; ++s) {
      const float4 x = *(const float4*)(inputs + ((size_t)(sbase + s) << 2));
      const float z = x.x*b0 + x.y*b1 + x.z*b2 + x.w*b3;
      const float szn = __sinf(z), czn = __cosf(z);
      const float u0 = iscos ? czn : szn;
      const float dz = iscos ? -szn : czn;
      const int m0 = 4*s;
      *(uint16_t*)(smem + cb + (((m0+0) ^ xm) << 4)) = f2h_bits(u0);
      *(uint16_t*)(smem + cb + (((m0+1) ^ xm) << 4)) = f2h_bits(dz*b1);
      *(uint16_t*)(smem + cb + (((m0+2) ^ xm) << 4)) = f2h_bits(dz*b2);
      *(uint16_t*)(smem + cb + (((m0+3) ^ xm) << 4)) = f2h_bits(dz*b3);
    }
  }
  __syncthreads();

  // A-frag per-lane base pointers: even/odd k-tile parity
  const char* paE = smem + ((kh << 10) + ((l31 ^ (kh << 2)) << 4));
  const char* paO = smem + ((kh << 10) + ((l31 ^ (kh << 2) ^ 2) << 4));

  f16x8 aC[MT], aN[MT];
  #pragma unroll
  for (int Mt = 0; Mt < MT; ++Mt)
    aC[Mt] = *(const f16x8*)(paE + Mt*512);          // ks = 0

  const f32x16 zz = {0,0,0,0,0,0,0,0,0,0,0,0,0,0,0,0};
  f32x16 acc[MT][2];

  for (int l = 0; l < NL; ++l) {
    #pragma unroll
    for (int Mt = 0; Mt < MT; ++Mt) { acc[Mt][0] = zz; acc[Mt][1] = zz; }
    const int g2b = l*NKS;
    int aoff = 0;

    #pragma unroll 1
    for (int t = 0; t < NKS/2; ++t) {
      // prefetch A k-tile (ks+1)
      #pragma unroll
      for (int Mt = 0; Mt < MT; ++Mt)
        aN[Mt] = *(const f16x8*)(paO + aoff + 2048 + Mt*512);
      __builtin_amdgcn_s_setprio(1);
      #pragma unroll
      for (int Mt = 0; Mt < MT; ++Mt) {
        acc[Mt][0] = __builtin_amdgcn_mfma_f32_32x32x16_f16(aC[Mt], bA0, acc[Mt][0], 0, 0, 0);
        acc[Mt][1] = __builtin_amdgcn_mfma_f32_32x32x16_f16(aC[Mt], bA1, acc[Mt][1], 0, 0, 0);
      }
      __builtin_amdgcn_s_setprio(0);
      {
        int gt = g2b + 2*t + 2;                  // reload freed B buffer, 2 ks ahead
        if (gt > NG2-1) gt = NG2-1;              // branchless clamp (tail only)
        const char* p = wp + ((size_t)gt << 14) + boff;
        bA0 = *(const f16x8*)p;
        bA1 = *(const f16x8*)(p + 1024);
      }
      if (t + 1 < NKS/2) {                       // prefetch A k-tile (ks+2)
        #pragma unroll
        for (int Mt = 0; Mt < MT; ++Mt)
          aC[Mt] = *(const f16x8*)(paE + aoff + 4096 + Mt*512);
      }
      __builtin_amdgcn_s_setprio(1);
      #pragma unroll
      for (int Mt = 0; Mt < MT; ++Mt) {
        acc[Mt][0] = __builtin_amdgcn_mfma_f32_32x32x16_f16(aN[Mt], bB0, acc[Mt][0], 0, 0, 0);
        acc[Mt][1] = __builtin_amdgcn_mfma_f32_32x32x16_f16(aN[Mt], bB1, acc[Mt][1], 0, 0, 0);
      }
      __builtin_amdgcn_s_setprio(0);
      {
        int gt = g2b + 2*t + 3;
        if (gt > NG2-1) gt = NG2-1;
        const char* p = wp + ((size_t)gt << 14) + boff;
        bB0 = *(const f16x8*)p;
        bB1 = *(const f16x8*)(p + 1024);
      }
      aoff += 4096;
    }
    __syncthreads();   // all A-reads of layer l complete before overwrite

    // ---- epilogue: h=(1+a)(dot+b); u'=sin h; du'=(1+a)cos(h)*dot_t ----
    // 32x32 C/D layout: col = lane&31, row = (r&3) + 8*(r>>2) + 4*(lane>>5)
    const float opa = 1.0f + alphas[l];
    #pragma unroll
    for (int Nt = 0; Nt < 2; ++Nt) {
      const int nc = wv*64 + Nt*32 + l31;
      const int cb = ((nc >> 4) << 11) + (((nc >> 3) & 1) << 10) + ((nc & 7) << 1);
      const int xm = (((nc >> 3) & 1) << 2) ^ (((nc >> 4) & 1) << 1);
      const float bias = bs[l*NN + nc];
      #pragma unroll
      for (int Mt = 0; Mt < MT; ++Mt) {
        const f32x16 c = acc[Mt][Nt];
        #pragma unroll
        for (int j = 0; j < 4; ++j) {
          const float hh = opa * (c[4*j] + bias);
          const float un = __sinf(hh);
          const float fc = opa * __cosf(hh);
          const float vv[4] = { un, fc*c[4*j+1], fc*c[4*j+2], fc*c[4*j+3] };
          const int m0 = Mt*32 + 8*j + 4*kh;
          #pragma unroll
          for (int s = 0; s < 4; ++s) {
            const int m = m0 + s;
            *(uint16_t*)(smem + cb + ((m ^ xm) << 4)) = f2h_bits(vv[s]);
          }
        }
      }
    }
    __syncthreads();

    if (l + 1 < NL) {   // preload ks=0 of next layer
      #pragma unroll
      for (int Mt = 0; Mt < MT; ++Mt)
        aC[Mt] = *(const f16x8*)(paE + Mt*512);
    }
  }

  // ---- final projection: dp[m][o] = sum_k A[m][k]*Wf[k][o] * scale[o] ----
  float* dp = (float*)(smem + LDS_A);
  const float4 sc4 = *(const float4*)scl;
  for (int rr = 0; rr < MROWS/8; ++rr) {     // 8 rows per wave
    const int m = wv*(MROWS/8) + rr;
    float p0 = 0.f, p1 = 0.f, p2 = 0.f, p3 = 0.f;
    #pragma unroll
    for (int j = 0; j < 8; ++j) {
      const int k = lane + j*64;
      float a = h2f(*(const uint16_t*)(smem + abyte(m, k)));
      float4 wf = ((const float4*)Wf)[k];
      p0 += a*wf.x; p1 += a*wf.y; p2 += a*wf.z; p3 += a*wf.w;
    }
    #pragma unroll
    for (int d = 1; d < 64; d <<= 1) {
      p0 += __shfl_xor(p0, d, 64);
      p1 += __shfl_xor(p1, d, 64);
      p2 += __shfl_xor(p2, d, 64);
      p3 += __shfl_xor(p3, d, 64);
    }
    if (lane == 0) {
      float4* o = (float4*)(dp + m*4);
      *o = make_float4(p0*sc4.x, p1*sc4.y, p2*sc4.z, p3*sc4.w);
    }
  }
  __syncthreads();

  // rows 4s+1=dPdz, 4s+2=dPdx, 4s+3=dPdy
  // u = dPdy[2]-dPdz[1]+dPdx[3]; v = dPdz[0]-dPdx[2]+dPdy[3]; w = dPdx[1]-dPdy[0]+dPdz[3]
  if (tid < SPB*3) {
    const int sl = tid / 3, c = tid - sl*3;
    const float* d1 = dp + (sl*4 + 1)*4;
    const float* d2 = dp + (sl*4 + 2)*4;
    const float* d3 = dp + (sl*4 + 3)*4;
    float val;
    if (c == 0)      val = d3[2] - d1[1] + d2[3];
    else if (c == 1) val = d1[0] - d2[2] + d3[3];
    else             val = d2[1] - d3[0] + d1[3];
    out[(size_t)(sbase + sl)*3 + c] = val;
  }
}

extern "C" void kernel_launch(void* const* d_in, const int* in_sizes, int n_in,
                              void* d_out, int out_size, void* d_ws, size_t ws_size,
                              hipStream_t stream) {
  const float* inputs = (const float*)d_in[0];
  const float* Brff   = (const float*)d_in[1];
  const float* Ws     = (const float*)d_in[2];
  const float* bsp    = (const float*)d_in[3];
  const float* alph   = (const float*)d_in[4];
  const float* Wfp    = (const float*)d_in[5];
  const float* sclp   = (const float*)d_in[6];
  uint16_t* wimg = (uint16_t*)d_ws;           // needs 4 MiB workspace

  prep_weights<<<NG2, 512, 0, stream>>>(Ws, wimg);
  const int nblocks = B_SZ / SPB;             // 4096
  pinn_fused<<<nblocks, 512, LDS_TOTAL, stream>>>(inputs, Brff, bsp, alph, Wfp, sclp,
                                                  wimg, (float*)d_out);
}